// Round 1
// 156.142 us; speedup vs baseline: 1.1048x; 1.1048x over previous
//
#include <hip/hip_runtime.h>

// CARAFE on MI355X. B=4, C=256, H=W=64, CMID=64, NK=100 (s=2, k=5).
// k0a: w1 -> w1c bf16 [c8][kk][q][oc][8ic]  (exact per-chunk LDS image for k1)
// k1 : conv3x3+relu as bf16 MFMA implicit GEMM, 512 thr, async A-staging -> featb bf16 NHWC
// k2 : conv1x1 (64->100) + softmax -> kern fp32 [bh][k(25)][w(64)][s(4)] (k3-ready layout)
// k3 : reassembly + pixel shuffle. v2: kern read DIRECTLY from global (coalesced f32x4,
//      L1/L2-resident, shared by all 4 waves + 16 chunk-blocks per bh) instead of LDS
//      staging -> LDS 53KB->27KB, occupancy 2-3 -> 5 blocks/CU.
// out[b, s*64 + c/4, 2h + (c%4)/2, 2w + (c%4)%2] = sum_k kern[b,s*25+k,h,w] * xpad[b,c,h+kh-2,w+kw-2]

#define BB 4
#define CC 256
#define HH 64
#define WW 64
#define CMID 64
#define NKCH 100

typedef __bf16 bf16;
typedef __bf16 bf16x8 __attribute__((ext_vector_type(8)));
typedef float f32x4 __attribute__((ext_vector_type(4)));

__device__ __forceinline__ void async_copy16(const void* gsrc, void* ldst) {
    __builtin_amdgcn_global_load_lds(
        (__attribute__((address_space(1))) void*)(void*)gsrc,
        (__attribute__((address_space(3))) void*)ldst, 16, 0, 0);
}

// ---------------- k0a: w1 [oc][ic][3][3] fp32 -> w1c bf16 [c8][kk][q][oc][8] ----------------
__global__ void k0a_transform(const float* __restrict__ w1, bf16* __restrict__ w1c) {
    int idx = blockIdx.x * 256 + threadIdx.x;
    if (idx >= 147456) return;
    int i8 = idx & 7;
    int oc = (idx >> 3) & 63;
    int q  = (idx >> 9) & 3;
    int t2 = idx >> 11;            // 0..71
    int kk = t2 % 9;
    int c8 = t2 / 9;
    int ic = c8 * 32 + q * 8 + i8;
    w1c[idx] = (bf16)w1[(oc * 256 + ic) * 9 + kk];
}

// ---------------- k1: conv3x3 (256->64) + relu via MFMA -> featb bf16 NHWC ----------------
// grid 256 (bh), 512 threads = 8 waves. Wave (mhalf=wid&1, nq=wid>>1): 32oc x 16px tile.
__global__ __launch_bounds__(512) void k1_mfma(const float* __restrict__ x,
        const bf16* __restrict__ w1c, const float* __restrict__ b1,
        bf16* __restrict__ featb) {
    int bh = blockIdx.x;
    int b = bh >> 6, h = bh & 63;
    int tid = threadIdx.x;
    int lane = tid & 63, wid = tid >> 6;
    int l15 = lane & 15, quad = lane >> 4;
    int mhalf = wid & 1, nq = wid >> 1;

    __shared__ __align__(16) bf16 xs[3 * 66 * 40];   // [r][slot0..65][ic32+pad8]; stride 80B
    __shared__ __align__(16) bf16 wlds[36 * 512];    // [kk*4+q][oc][8ic] = chunk image

    for (int i = tid; i < 3 * 66 * 40; i += 512) xs[i] = (bf16)0.f;
    __syncthreads();

    f32x4 acc0 = {0.f, 0.f, 0.f, 0.f}, acc1 = {0.f, 0.f, 0.f, 0.f};
    const float* xb = x + (size_t)b * (CC * HH * WW);

    for (int c8 = 0; c8 < 8; ++c8) {
        // A: 36 async 1KB copies, dst = uniform base + lane*16 (contiguous image)
        for (int t = wid; t < 36; t += 8)
            async_copy16(w1c + (((c8 * 36 + t) << 9) + lane * 8), (void*)&wlds[t << 9]);
        // B: lane-coalesced fp32 row reads, packed bf16-pair ds_writes
        int ic0 = c8 * 32;
        #pragma unroll
        for (int j = 0; j < 6; ++j) {
            int task = wid + j * 8;          // 48 tasks: (p=task&15, r=task>>4)
            int p = task & 15, r = task >> 4;
            int hr = h - 1 + r;
            if (hr >= 0 && hr < HH) {
                const float* src = xb + ((size_t)(ic0 + 2 * p) * (HH * WW)) + hr * WW + lane;
                float f0 = src[0], f1 = src[HH * WW];
                union { bf16 hh[2]; unsigned u; } cv;
                cv.hh[0] = (bf16)f0; cv.hh[1] = (bf16)f1;
                *(unsigned*)&xs[(r * 66 + 1 + lane) * 40 + 2 * p] = cv.u;
            }
        }
        __syncthreads();   // drains ds_write + global_load_lds
        #pragma unroll
        for (int kk = 0; kk < 9; ++kk) {
            int r3 = kk / 3, kw = kk % 3;
            bf16x8 a0 = *(const bf16x8*)&wlds[((kk * 4 + quad) * 64 + mhalf * 32 + l15) * 8];
            bf16x8 a1 = *(const bf16x8*)&wlds[((kk * 4 + quad) * 64 + mhalf * 32 + 16 + l15) * 8];
            bf16x8 bf = *(const bf16x8*)&xs[(r3 * 66 + nq * 16 + l15 + kw) * 40 + quad * 8];
            acc0 = __builtin_amdgcn_mfma_f32_16x16x32_bf16(a0, bf, acc0, 0, 0, 0);
            acc1 = __builtin_amdgcn_mfma_f32_16x16x32_bf16(a1, bf, acc1, 0, 0, 0);
        }
        __syncthreads();
    }

    // epilogue: D col(l15)=px, row(quad*4+reg)=oc (within 16x16 tile)
    int px = nq * 16 + l15;
    #pragma unroll
    for (int mi = 0; mi < 2; ++mi) {
        int oc0 = mhalf * 32 + mi * 16 + quad * 4;
        float4 bv = *(const float4*)&b1[oc0];
        f32x4 v = mi ? acc1 : acc0;
        union { bf16 hh[4]; uint2 u; } o;
        o.hh[0] = (bf16)fmaxf(v[0] + bv.x, 0.f);
        o.hh[1] = (bf16)fmaxf(v[1] + bv.y, 0.f);
        o.hh[2] = (bf16)fmaxf(v[2] + bv.z, 0.f);
        o.hh[3] = (bf16)fmaxf(v[3] + bv.w, 0.f);
        *(uint2*)&featb[((size_t)bh * 64 + px) * 64 + oc0] = o.u;
    }
}

// ---------------- k2: conv1x1 (64->100) + softmax -> kern [bh][k][w][s] ----------------
__global__ __launch_bounds__(256) void k2_kernelpred(const bf16* __restrict__ featb,
        const float* __restrict__ w2, const float* __restrict__ b2,
        float* __restrict__ kern) {
    int bh = blockIdx.x;
    int tid = threadIdx.x;
    int w = tid & 63;
    int s = tid >> 6;                 // softmax channel = s*25 + k

    __shared__ float fs[64 * 65];
    __shared__ __align__(16) float ws2[NKCH * 64];
    __shared__ float red[2][4][64];
    __shared__ __align__(16) float kts[25 * 64 * 4];   // [k][w][s]

    for (int i = tid; i < 64 * 64; i += 256) {
        int ic = i & 63;
        int ww = i >> 6;
        fs[ic * 65 + ww] = (float)featb[(size_t)bh * 4096 + i];
    }
    for (int i = tid; i < NKCH * 64; i += 256) ws2[i] = w2[i];
    __syncthreads();

    float4 fv[16];
    #pragma unroll
    for (int q = 0; q < 16; ++q) {
        fv[q].x = fs[(4 * q + 0) * 65 + w];
        fv[q].y = fs[(4 * q + 1) * 65 + w];
        fv[q].z = fs[(4 * q + 2) * 65 + w];
        fv[q].w = fs[(4 * q + 3) * 65 + w];
    }

    float lg[25];
    for (int i = 0; i < 25; ++i) {
        int oc = s * 25 + i;
        float a = b2[oc];
        const float4* wr = (const float4*)&ws2[oc * 64];   // wave-uniform broadcast
        #pragma unroll
        for (int q = 0; q < 16; ++q) {
            float4 wv = wr[q];
            a += fv[q].x * wv.x + fv[q].y * wv.y + fv[q].z * wv.z + fv[q].w * wv.w;
        }
        lg[i] = a;
    }

    float m = -1e30f;
    #pragma unroll
    for (int i = 0; i < 25; ++i) m = fmaxf(m, lg[i]);
    red[0][s][w] = m;
    __syncthreads();
    m = fmaxf(fmaxf(red[0][0][w], red[0][1][w]), fmaxf(red[0][2][w], red[0][3][w]));
    float ssum = 0.f;
    #pragma unroll
    for (int i = 0; i < 25; ++i) { lg[i] = __expf(lg[i] - m); ssum += lg[i]; }
    red[1][s][w] = ssum;
    __syncthreads();
    ssum = red[1][0][w] + red[1][1][w] + red[1][2][w] + red[1][3][w];
    float inv = 1.f / ssum;
    #pragma unroll
    for (int i = 0; i < 25; ++i) kts[(i * 64 + w) * 4 + s] = lg[i] * inv;
    __syncthreads();
    // coalesced float4 store of the transposed block
    float* kout = kern + (size_t)bh * 6400;
    for (int i = tid; i < 1600; i += 256)
        *(float4*)&kout[i * 4] = *(const float4*)&kts[i * 4];
}

// ---------------- k3: reassembly + pixel shuffle (v2: kern direct from global) ----------------
// grid (16, 256): chunk of 16 channels x bh. 256 thr: w=tid&63, cg=tid>>6 -> 4 channels each.
// LDS holds only the x tile (27.2 KB) -> 5 blocks/CU (was 2-3 at 53 KB).
// kern row (25.6 KB per bh) is read as coalesced 1KB/wave f32x4 loads straight from
// global; it is shared by all 4 waves and all 16 chunk-blocks of a bh -> L1/L2-hit.
__global__ __launch_bounds__(256, 5) void k3_reassemble(const float* __restrict__ x,
        const float* __restrict__ kern, float* __restrict__ out) {
    int chunk = blockIdx.x;
    int bh = blockIdx.y;
    int b = bh >> 6, h = bh & 63;
    int tid = threadIdx.x;
    int w = tid & 63;
    int cg = tid >> 6;

    __shared__ __align__(16) float xs[5 * 68 * 20];   // [r][slot0..67][cc16+pad4]; stride 80B

    // xs: lane-coalesced reads, stride-20 writes
    for (int i = tid; i < 16 * 5 * 64; i += 256) {
        int ww = i & 63;
        int rr = (i >> 6) % 5;
        int cc = i / 320;
        int hr = h - 2 + rr;
        float v = (hr >= 0 && hr < HH)
            ? x[(((size_t)b * CC + chunk * 16 + cc) * HH + hr) * WW + ww] : 0.f;
        xs[(rr * 68 + 2 + ww) * 20 + cc] = v;
    }
    for (int i = tid; i < 320; i += 256) {            // zero pad slots 0,1,66,67
        int cc = i & 15;
        int q = (i >> 4) & 3;
        int rr = i >> 6;
        int slot = (q < 2) ? q : (q + 64);
        xs[(rr * 68 + slot) * 20 + cc] = 0.f;
    }

    // kern row pointer for this (bh, w); lane-consecutive 16B -> 1KB/wave coalesced loads
    const float* kp = kern + (size_t)bh * 6400 + w * 4;

    // hoist r=0 kv loads above the barrier (no LDS dependency) for free latency overlap
    f32x4 kv0[5];
    #pragma unroll
    for (int kw = 0; kw < 5; ++kw)
        kv0[kw] = *(const f32x4*)&kp[kw * 256];

    __syncthreads();

    f32x4 a0 = {0.f,0.f,0.f,0.f}, a1 = {0.f,0.f,0.f,0.f};
    f32x4 a2 = {0.f,0.f,0.f,0.f}, a3 = {0.f,0.f,0.f,0.f};
    int cg4 = cg * 4;
    #pragma unroll
    for (int r = 0; r < 5; ++r) {
        #pragma unroll
        for (int kw = 0; kw < 5; ++kw) {
            f32x4 kv = (r == 0) ? kv0[kw]
                                : *(const f32x4*)&kp[(r * 5 + kw) * 256];
            f32x4 xv = *(const f32x4*)&xs[(r * 68 + w + kw) * 20 + cg4];
            a0 += kv.x * xv;
            a1 += kv.y * xv;
            a2 += kv.z * xv;
            a3 += kv.w * xv;
        }
    }

    int cq = chunk * 4 + cg;
    f32x4 accs[4] = {a0, a1, a2, a3};
    #pragma unroll
    for (int s = 0; s < 4; ++s) {
        size_t base = (((size_t)b * 256 + s * 64 + cq) * 128 + 2 * h) * 128 + 2 * w;
        *(float2*)&out[base]       = make_float2(accs[s][0], accs[s][1]);
        *(float2*)&out[base + 128] = make_float2(accs[s][2], accs[s][3]);
    }
}

extern "C" void kernel_launch(void* const* d_in, const int* in_sizes, int n_in,
                              void* d_out, int out_size, void* d_ws, size_t ws_size,
                              hipStream_t stream) {
    const float* x  = (const float*)d_in[0];
    const float* w1 = (const float*)d_in[1];
    const float* b1 = (const float*)d_in[2];
    const float* w2 = (const float*)d_in[3];
    const float* b2 = (const float*)d_in[4];
    float* out = (float*)d_out;

    char* wsb = (char*)d_ws;
    bf16*  featb = (bf16*)wsb;                   // 2,097,152 B
    float* kern  = (float*)(wsb + 2097152);      // 6,553,600 B
    bf16*  w1c   = (bf16*)(wsb + 8650752);       // 294,912 B

    k0a_transform<<<dim3(576), 256, 0, stream>>>(w1, w1c);
    k1_mfma<<<dim3(BB * HH), 512, 0, stream>>>(x, w1c, b1, featb);
    k2_kernelpred<<<dim3(BB * HH), 256, 0, stream>>>(featb, w2, b2, kern);
    k3_reassemble<<<dim3(16, BB * HH), 256, 0, stream>>>(x, kern, out);
}

// Round 3
// 141.979 us; speedup vs baseline: 1.2151x; 1.0998x over previous
//
#include <hip/hip_runtime.h>

// CARAFE on MI355X. B=4, C=256, H=W=64, CMID=64, NK=100 (s=2, k=5).
// v3b (v3 + softmax-reduction fix):
// k0a : LDS-tiled transpose w1 -> w1c bf16 [c8][kk][q][oc][8ic]; coalesced reads AND writes.
// k12 : FUSED conv3x3+relu (bf16 MFMA implicit GEMM) + conv1x1(64->100) + softmax
//       -> kern fp32 [bh][k(25)][w(64)][s(4)]. feat stays in LDS (fp32), never hits HBM.
//       Softmax is over the FULL 100-channel dim: with 25 logits split 13/12 across
//       wave pairs, the max/sum reduce must span ALL 8 wave slots (v3 bug: spanned 2).
//       T14 async-split: x rows for c8+1 loaded to regs right after staging barrier.
// k3  : reassembly + pixel shuffle, kern read direct from global (v2, unchanged).

#define BB 4
#define CC 256
#define HH 64
#define WW 64
#define CMID 64
#define NKCH 100

typedef __bf16 bf16;
typedef __bf16 bf16x8 __attribute__((ext_vector_type(8)));
typedef float f32x4 __attribute__((ext_vector_type(4)));

__device__ __forceinline__ void async_copy16(const void* gsrc, void* ldst) {
    __builtin_amdgcn_global_load_lds(
        (__attribute__((address_space(1))) void*)(void*)gsrc,
        (__attribute__((address_space(3))) void*)ldst, 16, 0, 0);
}

// ---------------- k0a: w1 [oc][ic][3][3] fp32 -> w1c bf16 [c8][kk][q][oc][8] ----------------
// grid (8 c8, 4 oc-quarters) x 256 thr. LDS tile 16oc x 288 (pad to 300).
// Reads: coalesced float4. Writes: oc-minor -> contiguous 16B stores.
__global__ void k0a_transform(const float* __restrict__ w1, bf16* __restrict__ w1c) {
    int c8 = blockIdx.x;          // 0..7
    int oq = blockIdx.y;          // 0..3
    int tid = threadIdx.x;
    __shared__ __align__(16) float wf[16 * 300];

    for (int i = tid; i < 16 * 72; i += 256) {
        int o = i / 72, r = i % 72;
        *(float4*)&wf[o * 300 + r * 4] =
            *(const float4*)&w1[(size_t)(oq * 16 + o) * 2304 + c8 * 288 + r * 4];
    }
    __syncthreads();

    for (int t = tid; t < 576; t += 256) {
        int o = t & 15, q = (t >> 4) & 3, kk = t >> 6;
        union { bf16 h[8]; uint4 u; } v;
        #pragma unroll
        for (int i8 = 0; i8 < 8; ++i8)
            v.h[i8] = (bf16)wf[o * 300 + (q * 8 + i8) * 9 + kk];
        *(uint4*)&w1c[(size_t)((((c8 * 9 + kk) * 4 + q) * 64) + oq * 16 + o) * 8] = v.u;
    }
}

// ---------------- k12: fused conv3x3+relu + conv1x1 + softmax ----------------
// grid 256 (bh), 512 threads = 8 waves. Conv: wave (mhalf=wid&1, nq=wid>>1) -> 32oc x 16px.
// Phase2: wave g -> softmax-group s2=g&3, oc-half (13/12 split).
__global__ __launch_bounds__(512) void k12_fused(const float* __restrict__ x,
        const bf16* __restrict__ w1c, const float* __restrict__ b1,
        const float* __restrict__ w2, const float* __restrict__ b2,
        float* __restrict__ kern) {
    int bh = blockIdx.x;
    int b = bh >> 6, h = bh & 63;
    int tid = threadIdx.x;
    int lane = tid & 63, wid = tid >> 6;
    int l15 = lane & 15, quad = lane >> 4;
    int mhalf = wid & 1, nq = wid >> 1;

    // LDS layout (99072 B): kts aliases wlds (dead after conv loop).
    __shared__ __align__(16) char smem[99072];
    bf16*  xs   = (bf16*)smem;                   // 15840 B (pad to 15872)
    bf16*  wlds = (bf16*)(smem + 15872);         // 36864 B
    float* kts  = (float*)(smem + 15872);        // 25600 B (alias wlds)
    float* fs   = (float*)(smem + 52736);        // 16640 B  [ic][w] stride 65
    float* ws2  = (float*)(smem + 69376);        // 25600 B  w2 copy
    float* red  = (float*)(smem + 94976);        // 4096 B   [2][8][64]

    // stage ws2 (needed only in phase 2; drains at first barrier, reads much later)
    for (int i = tid; i < 1600; i += 512)
        *(float4*)&ws2[i * 4] = *(const float4*)&w2[i * 4];

    for (int i = tid; i < 3 * 66 * 40; i += 512) xs[i] = (bf16)0.f;

    const float* xb = x + (size_t)b * (CC * HH * WW);

    // B-stage task geometry (constant across c8): task = wid + j*8 -> (p, r)
    int ppp[6], rrr[6];
    bool vmask[6];
    #pragma unroll
    for (int j = 0; j < 6; ++j) {
        int task = wid + j * 8;
        ppp[j] = task & 15;
        rrr[j] = task >> 4;
        int hr = h - 1 + rrr[j];
        vmask[j] = (hr >= 0 && hr < HH);
    }

    float f0[6], f1[6];
    #define LOADX(C8)                                                            \
        _Pragma("unroll")                                                        \
        for (int j = 0; j < 6; ++j) {                                            \
            if (vmask[j]) {                                                      \
                const float* src = xb + ((size_t)((C8) * 32 + 2 * ppp[j]) * (HH * WW)) \
                                 + (h - 1 + rrr[j]) * WW + lane;                 \
                f0[j] = src[0]; f1[j] = src[HH * WW];                            \
            }                                                                    \
        }

    LOADX(0)
    __syncthreads();          // xs zero-init complete (also orders ws2 staging)

    f32x4 acc0 = {0.f, 0.f, 0.f, 0.f}, acc1 = {0.f, 0.f, 0.f, 0.f};

    for (int c8 = 0; c8 < 8; ++c8) {
        // A: 36 async 1KB copies into wlds (freed by loop-end barrier)
        for (int t = wid; t < 36; t += 8)
            async_copy16(w1c + (((c8 * 36 + t) << 9) + lane * 8), (void*)&wlds[t << 9]);
        // B: pack prefetched regs -> bf16 pairs -> LDS
        #pragma unroll
        for (int j = 0; j < 6; ++j) {
            if (vmask[j]) {
                union { bf16 hh[2]; unsigned u; } cv;
                cv.hh[0] = (bf16)f0[j]; cv.hh[1] = (bf16)f1[j];
                *(unsigned*)&xs[(rrr[j] * 66 + 1 + lane) * 40 + 2 * ppp[j]] = cv.u;
            }
        }
        __syncthreads();      // drains ds_write + global_load_lds
        // T14: issue next c8's x loads NOW; latency hides under the MFMA phase
        if (c8 < 7) { LOADX(c8 + 1) }
        #pragma unroll
        for (int kk = 0; kk < 9; ++kk) {
            int r3 = kk / 3, kw = kk % 3;
            bf16x8 a0 = *(const bf16x8*)&wlds[((kk * 4 + quad) * 64 + mhalf * 32 + l15) * 8];
            bf16x8 a1 = *(const bf16x8*)&wlds[((kk * 4 + quad) * 64 + mhalf * 32 + 16 + l15) * 8];
            bf16x8 xv = *(const bf16x8*)&xs[(r3 * 66 + nq * 16 + l15 + kw) * 40 + quad * 8];
            acc0 = __builtin_amdgcn_mfma_f32_16x16x32_bf16(a0, xv, acc0, 0, 0, 0);
            acc1 = __builtin_amdgcn_mfma_f32_16x16x32_bf16(a1, xv, acc1, 0, 0, 0);
        }
        __syncthreads();
    }

    // conv epilogue: bias+relu, feat -> fs (fp32, LDS). D col(l15)=px, row(quad*4+reg)=oc.
    int px = nq * 16 + l15;
    #pragma unroll
    for (int mi = 0; mi < 2; ++mi) {
        int oc0 = mhalf * 32 + mi * 16 + quad * 4;
        float4 bv = *(const float4*)&b1[oc0];
        f32x4 v = mi ? acc1 : acc0;
        fs[(oc0 + 0) * 65 + px] = fmaxf(v[0] + bv.x, 0.f);
        fs[(oc0 + 1) * 65 + px] = fmaxf(v[1] + bv.y, 0.f);
        fs[(oc0 + 2) * 65 + px] = fmaxf(v[2] + bv.z, 0.f);
        fs[(oc0 + 3) * 65 + px] = fmaxf(v[3] + bv.w, 0.f);
    }
    __syncthreads();

    // ---- phase 2: conv1x1 (64->100) + softmax over FULL 100-channel dim, all 8 waves ----
    int w = lane;
    int g = wid, s2 = g & 3, ihalf = g >> 2;
    int i0 = ihalf ? 13 : 0;

    float4 fv[16];
    #pragma unroll
    for (int q = 0; q < 16; ++q) {
        fv[q].x = fs[(4 * q + 0) * 65 + w];
        fv[q].y = fs[(4 * q + 1) * 65 + w];
        fv[q].z = fs[(4 * q + 2) * 65 + w];
        fv[q].w = fs[(4 * q + 3) * 65 + w];
    }

    float lg[13];
    #pragma unroll
    for (int ii = 0; ii < 13; ++ii) {
        int idx = i0 + ii;
        bool act = (idx < 25);            // only false for ihalf=1, ii=12
        int oc = s2 * 25 + (act ? idx : 0);
        float a = b2[oc];
        const float4* wr = (const float4*)&ws2[oc * 64];   // wave-uniform broadcast
        #pragma unroll
        for (int q = 0; q < 16; ++q) {
            float4 wv = wr[q];
            a += fv[q].x * wv.x + fv[q].y * wv.y + fv[q].z * wv.z + fv[q].w * wv.w;
        }
        lg[ii] = act ? a : -1e30f;        // exp underflows to 0, max unaffected
    }

    float m = -1e30f;
    #pragma unroll
    for (int ii = 0; ii < 13; ++ii) m = fmaxf(m, lg[ii]);
    red[g * 64 + w] = m;
    __syncthreads();
    // softmax is over ALL 100 channels -> reduce across ALL 8 wave slots
    m = fmaxf(fmaxf(fmaxf(red[0 * 64 + w], red[1 * 64 + w]),
                    fmaxf(red[2 * 64 + w], red[3 * 64 + w])),
              fmaxf(fmaxf(red[4 * 64 + w], red[5 * 64 + w]),
                    fmaxf(red[6 * 64 + w], red[7 * 64 + w])));
    float ssum = 0.f;
    #pragma unroll
    for (int ii = 0; ii < 13; ++ii) { lg[ii] = __expf(lg[ii] - m); ssum += lg[ii]; }
    red[512 + g * 64 + w] = ssum;
    __syncthreads();
    ssum = ((red[512 + 0 * 64 + w] + red[512 + 1 * 64 + w]) +
            (red[512 + 2 * 64 + w] + red[512 + 3 * 64 + w])) +
           ((red[512 + 4 * 64 + w] + red[512 + 5 * 64 + w]) +
            (red[512 + 6 * 64 + w] + red[512 + 7 * 64 + w]));
    float inv = 1.f / ssum;
    #pragma unroll
    for (int ii = 0; ii < 13; ++ii)
        if (i0 + ii < 25) kts[((i0 + ii) * 64 + w) * 4 + s2] = lg[ii] * inv;
    __syncthreads();

    // coalesced float4 store of the transposed block [k][w][s]
    float* kout = kern + (size_t)bh * 6400;
    for (int i = tid; i < 1600; i += 512)
        *(float4*)&kout[i * 4] = *(const float4*)&kts[i * 4];
    #undef LOADX
}

// ---------------- k3: reassembly + pixel shuffle (v2: kern direct from global) ----------------
__global__ __launch_bounds__(256, 5) void k3_reassemble(const float* __restrict__ x,
        const float* __restrict__ kern, float* __restrict__ out) {
    int chunk = blockIdx.x;
    int bh = blockIdx.y;
    int b = bh >> 6, h = bh & 63;
    int tid = threadIdx.x;
    int w = tid & 63;
    int cg = tid >> 6;

    __shared__ __align__(16) float xs[5 * 68 * 20];   // [r][slot0..67][cc16+pad4]

    for (int i = tid; i < 16 * 5 * 64; i += 256) {
        int ww = i & 63;
        int rr = (i >> 6) % 5;
        int cc = i / 320;
        int hr = h - 2 + rr;
        float v = (hr >= 0 && hr < HH)
            ? x[(((size_t)b * CC + chunk * 16 + cc) * HH + hr) * WW + ww] : 0.f;
        xs[(rr * 68 + 2 + ww) * 20 + cc] = v;
    }
    for (int i = tid; i < 320; i += 256) {            // zero pad slots 0,1,66,67
        int cc = i & 15;
        int q = (i >> 4) & 3;
        int rr = i >> 6;
        int slot = (q < 2) ? q : (q + 64);
        xs[(rr * 68 + slot) * 20 + cc] = 0.f;
    }

    const float* kp = kern + (size_t)bh * 6400 + w * 4;

    f32x4 kv0[5];
    #pragma unroll
    for (int kw = 0; kw < 5; ++kw)
        kv0[kw] = *(const f32x4*)&kp[kw * 256];

    __syncthreads();

    f32x4 a0 = {0.f,0.f,0.f,0.f}, a1 = {0.f,0.f,0.f,0.f};
    f32x4 a2 = {0.f,0.f,0.f,0.f}, a3 = {0.f,0.f,0.f,0.f};
    int cg4 = cg * 4;
    #pragma unroll
    for (int r = 0; r < 5; ++r) {
        #pragma unroll
        for (int kw = 0; kw < 5; ++kw) {
            f32x4 kv = (r == 0) ? kv0[kw]
                                : *(const f32x4*)&kp[(r * 5 + kw) * 256];
            f32x4 xv = *(const f32x4*)&xs[(r * 68 + w + kw) * 20 + cg4];
            a0 += kv.x * xv;
            a1 += kv.y * xv;
            a2 += kv.z * xv;
            a3 += kv.w * xv;
        }
    }

    int cq = chunk * 4 + cg;
    f32x4 accs[4] = {a0, a1, a2, a3};
    #pragma unroll
    for (int s = 0; s < 4; ++s) {
        size_t base = (((size_t)b * 256 + s * 64 + cq) * 128 + 2 * h) * 128 + 2 * w;
        *(float2*)&out[base]       = make_float2(accs[s][0], accs[s][1]);
        *(float2*)&out[base + 128] = make_float2(accs[s][2], accs[s][3]);
    }
}

extern "C" void kernel_launch(void* const* d_in, const int* in_sizes, int n_in,
                              void* d_out, int out_size, void* d_ws, size_t ws_size,
                              hipStream_t stream) {
    const float* x  = (const float*)d_in[0];
    const float* w1 = (const float*)d_in[1];
    const float* b1 = (const float*)d_in[2];
    const float* w2 = (const float*)d_in[3];
    const float* b2 = (const float*)d_in[4];
    float* out = (float*)d_out;

    char* wsb = (char*)d_ws;
    float* kern = (float*)wsb;                   // 6,553,600 B
    bf16*  w1c  = (bf16*)(wsb + 6553600);        // 294,912 B

    k0a_transform<<<dim3(8, 4), 256, 0, stream>>>(w1, w1c);
    k12_fused<<<dim3(BB * HH), 512, 0, stream>>>(x, w1c, b1, w2, b2, kern);
    k3_reassemble<<<dim3(16, BB * HH), 256, 0, stream>>>(x, kern, out);
}

// Round 5
// 132.645 us; speedup vs baseline: 1.3006x; 1.0704x over previous
//
#include <hip/hip_runtime.h>

// CARAFE on MI355X. B=4, C=256, H=W=64, CMID=64, NK=100 (s=2, k=5).
// v4b (v4 + prefetch-guard fix: LOADX(c8+3) guard was c8<4, skipping the chunk-7
//      x load; chunk 7 then used stale chunk-5 registers -> absmax 2e-2. Now c8<6.)
// k0a : LDS-tiled transpose w1 -> w1c bf16 [c8][kk][q][oc][8ic].
// k12 : fused conv3x3+relu (MFMA) + conv1x1 + softmax. T3 2-phase pipeline:
//       double-buffered xs/wlds, stage(t+1) issued BEFORE MFMA(t), ONE barrier/iter;
//       x-prefetch regs ping-pong (fA/fB). w2 read wave-uniform from L2 in phase 2.
// k3  : reassembly + pixel shuffle. xs[r][g][slotSW][c4] with XOR swizzle
//       slot^=(slot>>3)&7 -> conflict-free ds_read_b128; float4 staging; LDS 21.8KB.

#define BB 4
#define CC 256
#define HH 64
#define WW 64
#define CMID 64
#define NKCH 100

typedef __bf16 bf16;
typedef __bf16 bf16x8 __attribute__((ext_vector_type(8)));
typedef float f32x4 __attribute__((ext_vector_type(4)));

__device__ __forceinline__ void async_copy16(const void* gsrc, void* ldst) {
    __builtin_amdgcn_global_load_lds(
        (__attribute__((address_space(1))) void*)(void*)gsrc,
        (__attribute__((address_space(3))) void*)ldst, 16, 0, 0);
}

// ---------------- k0a: w1 [oc][ic][3][3] fp32 -> w1c bf16 [c8][kk][q][oc][8] ----------------
__global__ void k0a_transform(const float* __restrict__ w1, bf16* __restrict__ w1c) {
    int c8 = blockIdx.x;          // 0..7
    int oq = blockIdx.y;          // 0..3
    int tid = threadIdx.x;
    __shared__ __align__(16) float wf[16 * 300];

    for (int i = tid; i < 16 * 72; i += 256) {
        int o = i / 72, r = i % 72;
        *(float4*)&wf[o * 300 + r * 4] =
            *(const float4*)&w1[(size_t)(oq * 16 + o) * 2304 + c8 * 288 + r * 4];
    }
    __syncthreads();

    for (int t = tid; t < 576; t += 256) {
        int o = t & 15, q = (t >> 4) & 3, kk = t >> 6;
        union { bf16 h[8]; uint4 u; } v;
        #pragma unroll
        for (int i8 = 0; i8 < 8; ++i8)
            v.h[i8] = (bf16)wf[o * 300 + (q * 8 + i8) * 9 + kk];
        *(uint4*)&w1c[(size_t)((((c8 * 9 + kk) * 4 + q) * 64) + oq * 16 + o) * 8] = v.u;
    }
}

// ---------------- k12: fused conv3x3+relu + conv1x1 + softmax, 2-phase pipelined ----------------
// grid 256 (bh), 512 threads = 8 waves. Conv: wave (mhalf=wid&1, nq=wid>>1) -> 32oc x 16px.
__global__ __launch_bounds__(512) void k12_fused(const float* __restrict__ x,
        const bf16* __restrict__ w1c, const float* __restrict__ b1,
        const float* __restrict__ w2, const float* __restrict__ b2,
        float* __restrict__ kern) {
    int bh = blockIdx.x;
    int b = bh >> 6, h = bh & 63;
    int tid = threadIdx.x;
    int lane = tid & 63, wid = tid >> 6;
    int l15 = lane & 15, quad = lane >> 4;
    int mhalf = wid & 1, nq = wid >> 1;

    // LDS 122112 B: xs0@0, xs1@15872, wl0@31744, wl1@68608, fs@105472(16640).
    // kts aliases wl0; red aliases xs0 (both dead after conv loop).
    __shared__ __align__(16) char smem[122112];
    bf16*  xs0  = (bf16*)smem;
    bf16*  xs1  = (bf16*)(smem + 15872);
    bf16*  wl0  = (bf16*)(smem + 31744);
    bf16*  wl1  = (bf16*)(smem + 68608);
    float* fs   = (float*)(smem + 105472);
    float* kts  = (float*)(smem + 31744);        // alias wl0 (25600 <= 36864)
    float* red  = (float*)smem;                  // alias xs0 (4096 <= 15872)

    const float* xb = x + (size_t)b * (CC * HH * WW);

    // B-stage task geometry (constant across c8): task = wid + j*8 -> (p, r)
    int ppp[6], rrr[6];
    bool vmask[6];
    #pragma unroll
    for (int j = 0; j < 6; ++j) {
        int task = wid + j * 8;
        ppp[j] = task & 15;
        rrr[j] = task >> 4;
        int hr = h - 1 + rrr[j];
        vmask[j] = (hr >= 0 && hr < HH);
    }

    float fA0[6], fA1[6], fB0[6], fB1[6];
    #define LOADX(C8, F0, F1)                                                    \
        _Pragma("unroll")                                                        \
        for (int j = 0; j < 6; ++j) {                                            \
            if (vmask[j]) {                                                      \
                const float* src = xb + ((size_t)((C8) * 32 + 2 * ppp[j]) * (HH * WW)) \
                                 + (h - 1 + rrr[j]) * WW + lane;                 \
                F0[j] = src[0]; F1[j] = src[HH * WW];                            \
            }                                                                    \
        }
    #define WRITEB(F0, F1, XSDST)                                                \
        _Pragma("unroll")                                                        \
        for (int j = 0; j < 6; ++j) {                                            \
            if (vmask[j]) {                                                      \
                union { bf16 hh[2]; unsigned u; } cv;                            \
                cv.hh[0] = (bf16)F0[j]; cv.hh[1] = (bf16)F1[j];                  \
                *(unsigned*)&XSDST[(rrr[j] * 66 + 1 + lane) * 40 + 2 * ppp[j]] = cv.u; \
            }                                                                    \
        }
    #define ACOPY(C8, WDST)                                                      \
        for (int t = wid; t < 36; t += 8)                                        \
            async_copy16(w1c + ((((C8) * 36 + t) << 9) + lane * 8), (void*)&WDST[t << 9]);
    #define MFMAS(XSRC, WSRC)                                                    \
        _Pragma("unroll")                                                        \
        for (int kk = 0; kk < 9; ++kk) {                                         \
            int r3 = kk / 3, kw = kk % 3;                                        \
            bf16x8 a0 = *(const bf16x8*)&WSRC[((kk * 4 + quad) * 64 + mhalf * 32 + l15) * 8]; \
            bf16x8 a1 = *(const bf16x8*)&WSRC[((kk * 4 + quad) * 64 + mhalf * 32 + 16 + l15) * 8]; \
            bf16x8 xv = *(const bf16x8*)&XSRC[(r3 * 66 + nq * 16 + l15 + kw) * 40 + quad * 8]; \
            acc0 = __builtin_amdgcn_mfma_f32_16x16x32_bf16(a0, xv, acc0, 0, 0, 0); \
            acc1 = __builtin_amdgcn_mfma_f32_16x16x32_bf16(a1, xv, acc1, 0, 0, 0); \
        }

    // prologue
    for (int i = tid; i < 7936; i += 512) { xs0[i] = (bf16)0.f; xs1[i] = (bf16)0.f; }
    LOADX(0, fA0, fA1)
    ACOPY(0, wl0)
    __syncthreads();                 // zero-init visible before interior writes
    WRITEB(fA0, fA1, xs0)
    LOADX(1, fB0, fB1)
    __syncthreads();                 // buf0 ready (A(0) drained by barrier's vmcnt)

    f32x4 acc0 = {0.f, 0.f, 0.f, 0.f}, acc1 = {0.f, 0.f, 0.f, 0.f};

    for (int c8 = 0; c8 < 8; c8 += 2) {
        // even iter: compute buf0, stage (c8+1) into buf1
        ACOPY(c8 + 1, wl1)
        MFMAS(xs0, wl0)
        WRITEB(fB0, fB1, xs1)
        if (c8 < 6) { LOADX(c8 + 2, fA0, fA1) }
        __syncthreads();
        // odd iter: compute buf1, stage (c8+2) into buf0
        if (c8 < 6) { ACOPY(c8 + 2, wl0) }
        MFMAS(xs1, wl1)
        if (c8 < 6) { WRITEB(fA0, fA1, xs0) }
        if (c8 < 6) { LOADX(c8 + 3, fB0, fB1) }   // FIX: was c8<4; chunk-7 load was skipped
        __syncthreads();
    }

    // conv epilogue: bias+relu, feat -> fs (fp32, LDS). D col(l15)=px, row(quad*4+reg)=oc.
    int px = nq * 16 + l15;
    #pragma unroll
    for (int mi = 0; mi < 2; ++mi) {
        int oc0 = mhalf * 32 + mi * 16 + quad * 4;
        float4 bv = *(const float4*)&b1[oc0];
        f32x4 v = mi ? acc1 : acc0;
        fs[(oc0 + 0) * 65 + px] = fmaxf(v[0] + bv.x, 0.f);
        fs[(oc0 + 1) * 65 + px] = fmaxf(v[1] + bv.y, 0.f);
        fs[(oc0 + 2) * 65 + px] = fmaxf(v[2] + bv.z, 0.f);
        fs[(oc0 + 3) * 65 + px] = fmaxf(v[3] + bv.w, 0.f);
    }
    __syncthreads();

    // ---- phase 2: conv1x1 (64->100) + softmax over FULL 100-channel dim, all 8 waves ----
    int w = lane;
    int g = wid, s2 = g & 3, ihalf = g >> 2;
    int i0 = ihalf ? 13 : 0;

    float4 fv[16];
    #pragma unroll
    for (int q = 0; q < 16; ++q) {
        fv[q].x = fs[(4 * q + 0) * 65 + w];
        fv[q].y = fs[(4 * q + 1) * 65 + w];
        fv[q].z = fs[(4 * q + 2) * 65 + w];
        fv[q].w = fs[(4 * q + 3) * 65 + w];
    }

    float lg[13];
    #pragma unroll
    for (int ii = 0; ii < 13; ++ii) {
        int idx = i0 + ii;
        bool act = (idx < 25);            // only false for ihalf=1, ii=12
        int oc = s2 * 25 + (act ? idx : 0);
        float a = b2[oc];
        const float4* wr = (const float4*)&w2[oc * 64];   // wave-uniform, L2-hot broadcast
        #pragma unroll
        for (int q = 0; q < 16; ++q) {
            float4 wv = wr[q];
            a += fv[q].x * wv.x + fv[q].y * wv.y + fv[q].z * wv.z + fv[q].w * wv.w;
        }
        lg[ii] = act ? a : -1e30f;        // exp underflows to 0, max unaffected
    }

    float m = -1e30f;
    #pragma unroll
    for (int ii = 0; ii < 13; ++ii) m = fmaxf(m, lg[ii]);
    red[g * 64 + w] = m;
    __syncthreads();
    // softmax over ALL 100 channels -> reduce across ALL 8 wave slots
    m = fmaxf(fmaxf(fmaxf(red[0 * 64 + w], red[1 * 64 + w]),
                    fmaxf(red[2 * 64 + w], red[3 * 64 + w])),
              fmaxf(fmaxf(red[4 * 64 + w], red[5 * 64 + w]),
                    fmaxf(red[6 * 64 + w], red[7 * 64 + w])));
    float ssum = 0.f;
    #pragma unroll
    for (int ii = 0; ii < 13; ++ii) { lg[ii] = __expf(lg[ii] - m); ssum += lg[ii]; }
    red[512 + g * 64 + w] = ssum;
    __syncthreads();
    ssum = ((red[512 + 0 * 64 + w] + red[512 + 1 * 64 + w]) +
            (red[512 + 2 * 64 + w] + red[512 + 3 * 64 + w])) +
           ((red[512 + 4 * 64 + w] + red[512 + 5 * 64 + w]) +
            (red[512 + 6 * 64 + w] + red[512 + 7 * 64 + w]));
    float inv = 1.f / ssum;
    #pragma unroll
    for (int ii = 0; ii < 13; ++ii)
        if (i0 + ii < 25) kts[((i0 + ii) * 64 + w) * 4 + s2] = lg[ii] * inv;
    __syncthreads();

    // coalesced float4 store of the transposed block [k][w][s]
    float* kout = kern + (size_t)bh * 6400;
    for (int i = tid; i < 1600; i += 512)
        *(float4*)&kout[i * 4] = *(const float4*)&kts[i * 4];
    #undef LOADX
    #undef WRITEB
    #undef ACOPY
    #undef MFMAS
}

// ---------------- k3: reassembly + pixel shuffle (conflict-free swizzled LDS) ----------------
// grid (16, 256). 256 thr: w=tid&63, cg=tid>>6 -> 4 channels each.
// xs[r][g][slotSW][c4]: slot swizzle sw = s ^ ((s>>3)&7) (bijective; identity at borders).
// Reads: lane-consecutive 16B -> conflict-free b128. Writes: 2-way (free).
__global__ __launch_bounds__(256, 6) void k3_reassemble(const float* __restrict__ x,
        const float* __restrict__ kern, float* __restrict__ out) {
    int chunk = blockIdx.x;
    int bh = blockIdx.y;
    int b = bh >> 6, h = bh & 63;
    int tid = threadIdx.x;
    int w = tid & 63;
    int cg = tid >> 6;

    __shared__ __align__(16) float xs[5 * 4 * 68 * 4];   // 21760 B

    // staging: 1280 float4 tasks (16 u x 16 cc x 5 rr), 5 per thread; coalesced 16B/lane
    #pragma unroll
    for (int k = 0; k < 5; ++k) {
        int idx = tid + k * 256;
        int u = idx & 15, cc = (idx >> 4) & 15, rr = idx >> 8;
        int hr = h - 2 + rr;
        float4 v = make_float4(0.f, 0.f, 0.f, 0.f);
        if (hr >= 0 && hr < HH)
            v = *(const float4*)&x[(((size_t)b * CC + chunk * 16 + cc) * HH + hr) * WW + 4 * u];
        int base = (rr * 4 + (cc >> 2)) * 68;
        int c = cc & 3;
        #pragma unroll
        for (int j = 0; j < 4; ++j) {
            int s = 2 + 4 * u + j;
            int sw = s ^ ((s >> 3) & 7);
            xs[(base + sw) * 4 + c] = ((const float*)&v)[j];
        }
    }
    // border zeros: slots 0,1,66,67 (sw = identity there) for all (r,g,c)
    for (int i = tid; i < 320; i += 256) {
        int c = i & 3;
        int q = (i >> 2) & 3;
        int rg = i >> 4;
        int slot = (q < 2) ? q : (q + 64);
        xs[(rg * 68 + slot) * 4 + c] = 0.f;
    }

    const float* kp = kern + (size_t)bh * 6400 + w * 4;
    f32x4 kv0[5];
    #pragma unroll
    for (int kw = 0; kw < 5; ++kw)
        kv0[kw] = *(const f32x4*)&kp[kw * 256];

    // per-lane swizzled slot indices (r-independent)
    int swk[5];
    #pragma unroll
    for (int kw = 0; kw < 5; ++kw) {
        int s = w + kw;
        swk[kw] = s ^ ((s >> 3) & 7);
    }

    __syncthreads();

    f32x4 a0 = {0.f,0.f,0.f,0.f}, a1 = {0.f,0.f,0.f,0.f};
    f32x4 a2 = {0.f,0.f,0.f,0.f}, a3 = {0.f,0.f,0.f,0.f};
    #pragma unroll
    for (int r = 0; r < 5; ++r) {
        #pragma unroll
        for (int kw = 0; kw < 5; ++kw) {
            f32x4 kv = (r == 0) ? kv0[kw]
                                : *(const f32x4*)&kp[(r * 5 + kw) * 256];
            f32x4 xv = *(const f32x4*)&xs[((r * 4 + cg) * 68 + swk[kw]) * 4];
            a0 += kv.x * xv;
            a1 += kv.y * xv;
            a2 += kv.z * xv;
            a3 += kv.w * xv;
        }
    }

    int cq = chunk * 4 + cg;
    f32x4 accs[4] = {a0, a1, a2, a3};
    #pragma unroll
    for (int s = 0; s < 4; ++s) {
        size_t base = (((size_t)b * 256 + s * 64 + cq) * 128 + 2 * h) * 128 + 2 * w;
        *(float2*)&out[base]       = make_float2(accs[s][0], accs[s][1]);
        *(float2*)&out[base + 128] = make_float2(accs[s][2], accs[s][3]);
    }
}

extern "C" void kernel_launch(void* const* d_in, const int* in_sizes, int n_in,
                              void* d_out, int out_size, void* d_ws, size_t ws_size,
                              hipStream_t stream) {
    const float* x  = (const float*)d_in[0];
    const float* w1 = (const float*)d_in[1];
    const float* b1 = (const float*)d_in[2];
    const float* w2 = (const float*)d_in[3];
    const float* b2 = (const float*)d_in[4];
    float* out = (float*)d_out;

    char* wsb = (char*)d_ws;
    float* kern = (float*)wsb;                   // 6,553,600 B
    bf16*  w1c  = (bf16*)(wsb + 6553600);        // 294,912 B

    k0a_transform<<<dim3(8, 4), 256, 0, stream>>>(w1, w1c);
    k12_fused<<<dim3(BB * HH), 512, 0, stream>>>(x, w1c, b1, w2, b2, kern);
    k3_reassemble<<<dim3(16, BB * HH), 256, 0, stream>>>(x, kern, out);
}